// Round 9
// baseline (17622.874 us; speedup 1.0000x reference)
//
#include <hip/hip_runtime.h>

#define B_ 256
#define T_ 1024
#define H_ 64

typedef float f32x2 __attribute__((ext_vector_type(2)));
typedef float f32x4 __attribute__((ext_vector_type(4)));

// fast sigmoid/tanh via v_exp_f32 + v_rcp_f32 (validated R2-R8: absmax 0.0)
__device__ __forceinline__ float fast_sigmoid(float x) {
    float e = __builtin_amdgcn_exp2f(-1.4426950408889634f * x);
    return __builtin_amdgcn_rcpf(1.0f + e);
}
__device__ __forceinline__ float fast_tanh(float x) {
    float e = __builtin_amdgcn_exp2f(2.8853900817779268f * x);
    return 1.0f - 2.0f * __builtin_amdgcn_rcpf(1.0f + e);
}

// butterfly add via DPP: 0xB1=quad_perm xor1, 0x4E=quad_perm xor2
template<int CTRL>
__device__ __forceinline__ float dpp_addf(float v) {
    int vi = __builtin_bit_cast(int, v);
    int sh = __builtin_amdgcn_update_dpp(0, vi, CTRL, 0xF, 0xF, true);
    return v + __builtin_bit_cast(float, sh);
}

// R8-validated: barrier draining LDS only (no vmcnt); all global loads have
// their own consumer waitcnts, and there is no in-place global hazard here.
__device__ __forceinline__ void block_sync_lds() {
    asm volatile("s_waitcnt lgkmcnt(0)\n\ts_barrier" ::: "memory");
}

__device__ __forceinline__ float hsum4(f32x4 v) { return (v.x + v.y) + (v.z + v.w); }

// ---------------------------------------------------------------------------
// PENTA: all 5 LSTM layers in one 640-thread block (one block per batch row).
// Role l (128 threads, 2 waves) runs layer l at t = s - l. Thread (u2, kc)
// owns 8 gate rows {g*64 + 2*u2 + p} (4 gates x 2 units) x one k-chunk:
//   role 0: chunk = 16 floats of h      (kc in [0,4), 128 pinned weights)
//   roles 1-4: chunk = 32 floats of [x|h] (kc in [0,4), 256 pinned weights)
// LDS: per-role double-buffered padded chunk vectors; chunk kc at kc*20 (role
// 0, banks {0,20,8,28}) or kc*36 (roles 1-4, banks {0,4,8,12}) -> all b128
// ingests conflict-free (validated R4/R8). DPP quad-reduce over kc lanes;
// kc==0 lane does 2 cell updates, writes h pairs as float2 to its own h-slot
// + downstream x-slot (role 4 -> global). Spine: 1028 steps for all 5 layers.
// ---------------------------------------------------------------------------
__global__ __attribute__((amdgpu_flat_work_group_size(640, 640)))
void lstm_penta(const float* __restrict__ x,      // [B,T]
                float* __restrict__ hout,         // [B,T,64] = h_L4
                const float* __restrict__ w_ih0,  // [256]
                const float* __restrict__ w_ihr,  // [4,256,64]
                const float* __restrict__ w_hh,   // [5,256,64]
                const float* __restrict__ b_ih,   // [5,256]
                const float* __restrict__ b_hh)   // [5,256]
{
    const int b    = blockIdx.x;
    const int tid  = threadIdx.x;
    const int role = tid >> 7;      // 0..4, wave-uniform
    const int loc  = tid & 127;
    const int kc   = loc & 3;
    const int u2   = loc >> 2;      // unit pair: units 2*u2, 2*u2+1

    // [role][parity][chunks]: role 0 uses 80 floats (4x20), roles 1-4 use 144 (4x36)
    __shared__ __align__(16) float bufs[5][2][144];

    // ---- weights into pinned registers ----
    f32x4 wt[8][8];                 // roles 1-4: [row][q0..7]; role 0: [row][q0..3]
    const float* wl_hh = w_hh + (long)role * 4 * H_ * H_;
    const float* wl_ih = (role >= 1) ? (w_ihr + (long)(role - 1) * 4 * H_ * H_) : nullptr;

    #pragma unroll
    for (int g = 0; g < 4; ++g)
        #pragma unroll
        for (int p = 0; p < 2; ++p) {
            const int r = g * 2 + p;
            const int row = g * H_ + 2 * u2 + p;
            if (role == 0) {
                const float* base = wl_hh + row * H_ + kc * 16;
                #pragma unroll
                for (int q = 0; q < 4; ++q)
                    wt[r][q] = *(const f32x4*)(base + 4 * q);
            } else {
                const float* base = (kc < 2) ? (wl_ih + row * H_ + kc * 32)
                                             : (wl_hh + row * H_ + (kc - 2) * 32);
                #pragma unroll
                for (int q = 0; q < 8; ++q)
                    wt[r][q] = *(const f32x4*)(base + 4 * q);
            }
        }
    if (role == 0) {
        #pragma unroll
        for (int r = 0; r < 8; ++r)
            #pragma unroll
            for (int q = 0; q < 4; ++q)
                asm volatile("" : "+v"(wt[r][q]));
    } else {
        #pragma unroll
        for (int r = 0; r < 8; ++r)
            #pragma unroll
            for (int q = 0; q < 8; ++q)
                asm volatile("" : "+v"(wt[r][q]));
    }

    // ---- kc==0 lane state: biases (+ L0 x-weights), 2 cell states ----
    float bias[8], w0[8];
    #pragma unroll
    for (int r = 0; r < 8; ++r) { bias[r] = 0.f; w0[r] = 0.f; }
    if (kc == 0) {
        #pragma unroll
        for (int g = 0; g < 4; ++g)
            #pragma unroll
            for (int p = 0; p < 2; ++p) {
                const int row = g * H_ + 2 * u2 + p;
                bias[g * 2 + p] = b_ih[role * 256 + row] + b_hh[role * 256 + row];
                if (role == 0) w0[g * 2 + p] = w_ih0[row];
            }
    }
    float c0 = 0.f, c1 = 0.f;
    float xt = (role == 0) ? x[(long)b * T_] : 0.f;

    // ---- LDS init: h-part of buf_l at parity (l&1) = 0 ----
    if (loc < H_) {
        const int u = loc;
        if (role == 0) bufs[0][0][(u >> 4) * 20 + (u & 15)] = 0.f;
        else           bufs[role][role & 1][((u >> 5) + 2) * 36 + (u & 31)] = 0.f;
    }
    block_sync_lds();

    for (int s = 0; s < T_ + 4; ++s) {
        const int rb = s & 1, wb = rb ^ 1;
        const bool active = (s >= role) && (s < T_ + role);
        float xn = 0.f;

        if (active) {
            // L0: prefetch next scalar x (uniform -> scalar load)
            if (role == 0 && s + 1 < T_) xn = x[(long)b * T_ + s + 1];

            // ---- ingest own chunk + 8-row FMA ----
            f32x4 a[8];
            #pragma unroll
            for (int r = 0; r < 8; ++r) a[r] = (f32x4){0.f, 0.f, 0.f, 0.f};

            if (role == 0) {
                const f32x4* xv = (const f32x4*)&bufs[0][rb][kc * 20];
                #pragma unroll
                for (int q = 0; q < 4; ++q) {
                    f32x4 hq = xv[q];
                    #pragma unroll
                    for (int r = 0; r < 8; ++r)
                        a[r] = __builtin_elementwise_fma(wt[r][q], hq, a[r]);
                }
            } else {
                const f32x4* xv = (const f32x4*)&bufs[role][rb][kc * 36];
                #pragma unroll
                for (int q = 0; q < 8; ++q) {
                    f32x4 hq = xv[q];
                    #pragma unroll
                    for (int r = 0; r < 8; ++r)
                        a[r] = __builtin_elementwise_fma(wt[r][q], hq, a[r]);
                }
            }

            float acc[8];
            #pragma unroll
            for (int r = 0; r < 8; ++r) acc[r] = hsum4(a[r]);
            #pragma unroll
            for (int r = 0; r < 8; ++r) acc[r] = dpp_addf<0xB1>(acc[r]);
            #pragma unroll
            for (int r = 0; r < 8; ++r) acc[r] = dpp_addf<0x4E>(acc[r]);

            // ---- cell update for units 2*u2 (p=0) and 2*u2+1 (p=1) ----
            if (kc == 0) {
                float h0v, h1v;
                {
                    float gi = acc[0] + bias[0] + w0[0] * xt;
                    float gf = acc[2] + bias[2] + w0[2] * xt;
                    float gg = acc[4] + bias[4] + w0[4] * xt;
                    float go = acc[6] + bias[6] + w0[6] * xt;
                    float i_ = fast_sigmoid(gi), f_ = fast_sigmoid(gf);
                    float g_ = fast_tanh(gg),   o_ = fast_sigmoid(go);
                    c0 = f_ * c0 + i_ * g_;
                    h0v = o_ * fast_tanh(c0);
                }
                {
                    float gi = acc[1] + bias[1] + w0[1] * xt;
                    float gf = acc[3] + bias[3] + w0[3] * xt;
                    float gg = acc[5] + bias[5] + w0[5] * xt;
                    float go = acc[7] + bias[7] + w0[7] * xt;
                    float i_ = fast_sigmoid(gi), f_ = fast_sigmoid(gf);
                    float g_ = fast_tanh(gg),   o_ = fast_sigmoid(go);
                    c1 = f_ * c1 + i_ * g_;
                    h1v = o_ * fast_tanh(c1);
                }
                const int u = 2 * u2;
                const f32x2 hpair = {h0v, h1v};
                // own recurrent h slot
                if (role == 0) *(f32x2*)&bufs[0][wb][(u >> 4) * 20 + (u & 15)] = hpair;
                else *(f32x2*)&bufs[role][wb][((u >> 5) + 2) * 36 + (u & 31)] = hpair;
                // downstream: x-slot of role+1, or global for role 4
                if (role < 4)
                    *(f32x2*)&bufs[role + 1][wb][(u >> 5) * 36 + (u & 31)] = hpair;
                else
                    *(f32x2*)&hout[((long)b * T_ + (s - 4)) * H_ + u] = hpair;
            }
        }
        block_sync_lds();
        if (role == 0) xt = xn;
    }
}

// MLP head (R3-R8-validated): wave-uniform W1 -> scalar loads. ~25 us.
__global__ __launch_bounds__(256)
void mlp_head_v2(const float* __restrict__ hbuf,
                 const float* __restrict__ W1,
                 const float* __restrict__ b1,
                 const float* __restrict__ W2,
                 const float* __restrict__ b2,
                 float* __restrict__ out)
{
    const long r = (long)blockIdx.x * 256 + threadIdx.x;

    float row[H_];
    const float4* src = (const float4*)(hbuf + r * H_);
    #pragma unroll
    for (int q = 0; q < 16; ++q) {
        float4 v = src[q];
        row[4*q+0] = fmaxf(v.x, 0.f); row[4*q+1] = fmaxf(v.y, 0.f);
        row[4*q+2] = fmaxf(v.z, 0.f); row[4*q+3] = fmaxf(v.w, 0.f);
    }
    #pragma unroll
    for (int q = 0; q < 16; ++q)
        asm volatile("" : "+v"(row[4*q]), "+v"(row[4*q+1]),
                         "+v"(row[4*q+2]), "+v"(row[4*q+3]));

    float acc = b2[0];
    for (int jj = 0; jj < H_; ++jj) {
        const float* wrow = W1 + jj * H_;
        float s0 = 0.f, s1 = 0.f, s2 = 0.f, s3 = 0.f;
        #pragma unroll
        for (int q = 0; q < 16; ++q) {
            s0 += row[4*q+0] * wrow[4*q+0];
            s1 += row[4*q+1] * wrow[4*q+1];
            s2 += row[4*q+2] * wrow[4*q+2];
            s3 += row[4*q+3] * wrow[4*q+3];
        }
        float y = fmaxf(b1[jj] + (s0 + s1) + (s2 + s3), 0.f);
        acc += y * W2[jj];
    }
    out[r] = acc;
}

extern "C" void kernel_launch(void* const* d_in, const int* in_sizes, int n_in,
                              void* d_out, int out_size, void* d_ws, size_t ws_size,
                              hipStream_t stream) {
    const float* x     = (const float*)d_in[0];   // [B,T,1]
    const float* w_ih0 = (const float*)d_in[1];   // [256]
    const float* w_ihr = (const float*)d_in[2];   // [4,256,64]
    const float* w_hh  = (const float*)d_in[3];   // [5,256,64]
    const float* b_ih  = (const float*)d_in[4];   // [5,256]
    const float* b_hh  = (const float*)d_in[5];   // [5,256]
    const float* W1    = (const float*)d_in[6];   // [64,64]
    const float* b1    = (const float*)d_in[7];   // [64]
    const float* W2    = (const float*)d_in[8];   // [64]
    const float* b2    = (const float*)d_in[9];   // [1]
    // d_in[10] = future (0)

    float* out = (float*)d_out;
    float* buf = (float*)d_ws;                    // [B,T,64] fp32 = 64 MB

    // all 5 LSTM layers, one kernel, 1028-step spine -> buf = h_L4
    lstm_penta<<<dim3(B_), dim3(640), 0, stream>>>(
        x, buf, w_ih0, w_ihr, w_hh, b_ih, b_hh);

    mlp_head_v2<<<dim3((B_ * T_) / 256), dim3(256), 0, stream>>>(
        buf, W1, b1, W2, b2, out);
}

// Round 10
// 3008.138 us; speedup vs baseline: 5.8584x; 5.8584x over previous
//
#include <hip/hip_runtime.h>

#define B_ 256
#define T_ 1024
#define H_ 64

typedef float f32x2 __attribute__((ext_vector_type(2)));
typedef float f32x4 __attribute__((ext_vector_type(4)));

// fast sigmoid/tanh via v_exp_f32 + v_rcp_f32 (validated R2-R9: absmax 0.0)
__device__ __forceinline__ float fast_sigmoid(float x) {
    float e = __builtin_amdgcn_exp2f(-1.4426950408889634f * x);
    return __builtin_amdgcn_rcpf(1.0f + e);
}
__device__ __forceinline__ float fast_tanh(float x) {
    float e = __builtin_amdgcn_exp2f(2.8853900817779268f * x);
    return 1.0f - 2.0f * __builtin_amdgcn_rcpf(1.0f + e);
}

// butterfly add via DPP: 0xB1=xor1, 0x4E=xor2, 0x141=half-mirror (=xor4 after 1,2)
// (3-stage chain over 8 lanes validated R3/R4)
template<int CTRL>
__device__ __forceinline__ float dpp_addf(float v) {
    int vi = __builtin_bit_cast(int, v);
    int sh = __builtin_amdgcn_update_dpp(0, vi, CTRL, 0xF, 0xF, true);
    return v + __builtin_bit_cast(float, sh);
}

// R8-validated: barrier draining LDS only (no vmcnt drain).
__device__ __forceinline__ void block_sync_lds() {
    asm volatile("s_waitcnt lgkmcnt(0)\n\ts_barrier" ::: "memory");
}

__device__ __forceinline__ float hsum4(f32x4 v) { return (v.x + v.y) + (v.z + v.w); }

// R10 geometry: thread owns 8 gate rows {g*64 + 2*u2 + p} (4 gates x 2 units)
// x one 16-float k-chunk -> 128 pinned weight floats (under the 256-ArchVGPR
// wall proven by R9's spill). 4 ds_read_b128/step/thread (half of R8).
// Chunk kc at float offset kc*20: the 8 chunk b128 addresses cover all 32
// banks disjointly (R4-validated) -> conflict-free broadcast reads.

// load 8 rows x 16-float chunk of weights and pin
__device__ __forceinline__ void load_pin_w8(const float* w_ih, const float* w_hh,
                                            int u2, int kc, bool ih_part,
                                            f32x4 wt[8][4]) {
    #pragma unroll
    for (int g = 0; g < 4; ++g)
        #pragma unroll
        for (int p = 0; p < 2; ++p) {
            const int row = g * H_ + 2 * u2 + p;
            const float* base = ih_part ? (w_ih + row * H_ + kc * 16)
                                        : (w_hh + row * H_ + (kc - 4) * 16);
            #pragma unroll
            for (int q = 0; q < 4; ++q)
                wt[g * 2 + p][q] = *(const f32x4*)(base + 4 * q);
        }
    #pragma unroll
    for (int r = 0; r < 8; ++r)
        #pragma unroll
        for (int q = 0; q < 4; ++q)
            asm volatile("" : "+v"(wt[r][q]));
}

// ingest own chunk (4 b128) + 8-row FMA + hsum
__device__ __forceinline__ void dot8(const float* chunk, const f32x4 wt[8][4],
                                     float acc[8]) {
    const f32x4* xv = (const f32x4*)chunk;
    f32x4 a[8];
    #pragma unroll
    for (int r = 0; r < 8; ++r) a[r] = (f32x4){0.f, 0.f, 0.f, 0.f};
    #pragma unroll
    for (int q = 0; q < 4; ++q) {
        f32x4 hq = xv[q];
        #pragma unroll
        for (int r = 0; r < 8; ++r)
            a[r] = __builtin_elementwise_fma(wt[r][q], hq, a[r]);
    }
    #pragma unroll
    for (int r = 0; r < 8; ++r) acc[r] = hsum4(a[r]);
}

// 2-unit cell update from reduced acc[8] (+ optional L0 scalar-x term)
__device__ __forceinline__ f32x2 cell2(const float acc[8], const float bias[8],
                                       const float w0[8], float xt,
                                       float& c0, float& c1) {
    float h0v, h1v;
    {
        float i_ = fast_sigmoid(acc[0] + bias[0] + w0[0] * xt);
        float f_ = fast_sigmoid(acc[2] + bias[2] + w0[2] * xt);
        float g_ = fast_tanh   (acc[4] + bias[4] + w0[4] * xt);
        float o_ = fast_sigmoid(acc[6] + bias[6] + w0[6] * xt);
        c0 = f_ * c0 + i_ * g_;
        h0v = o_ * fast_tanh(c0);
    }
    {
        float i_ = fast_sigmoid(acc[1] + bias[1] + w0[1] * xt);
        float f_ = fast_sigmoid(acc[3] + bias[3] + w0[3] * xt);
        float g_ = fast_tanh   (acc[5] + bias[5] + w0[5] * xt);
        float o_ = fast_sigmoid(acc[7] + bias[7] + w0[7] * xt);
        c1 = f_ * c1 + i_ * g_;
        h1v = o_ * fast_tanh(c1);
    }
    return (f32x2){h0v, h1v};
}

// ---------------------------------------------------------------------------
// K1: [L0 + L1] diagonal pair. A=L0 (128 thr, NCH=4 over h), B=L1 (256 thr,
// NCH=8 over [h_A|h_B]). 384 threads total.
// ---------------------------------------------------------------------------
__global__ __attribute__((amdgpu_flat_work_group_size(384, 384)))
void lstm_pair01(const float* __restrict__ xA,     // [B,T]
                 float* __restrict__ hB_out,       // [B,T,64] = h_L1
                 const float* __restrict__ wA_ih,  // [256] (scalar-x weights)
                 const float* __restrict__ wA_hh,  // [256,64]
                 const float* __restrict__ bA_ih,
                 const float* __restrict__ bA_hh,
                 const float* __restrict__ wB_ih,  // [256,64]
                 const float* __restrict__ wB_hh,  // [256,64]
                 const float* __restrict__ bB_ih,
                 const float* __restrict__ bB_hh)
{
    const int b   = blockIdx.x;
    const int tid = threadIdx.x;
    const bool isB = (tid < 256);

    __shared__ __align__(16) float xhA[2][80];    // L0 h: 4 chunks x 20
    __shared__ __align__(16) float xhB[2][160];   // [h_A | h_B]: 8 chunks x 20

    int kc, u2;
    f32x4 wt[8][4];
    float bias[8], w0[8];
    #pragma unroll
    for (int r = 0; r < 8; ++r) { bias[r] = 0.f; w0[r] = 0.f; }

    if (isB) {
        kc = tid & 7; u2 = tid >> 3;
        load_pin_w8(wB_ih, wB_hh, u2, kc, kc < 4, wt);
        if (kc == 0) {
            #pragma unroll
            for (int g = 0; g < 4; ++g)
                #pragma unroll
                for (int p = 0; p < 2; ++p) {
                    const int row = g * H_ + 2 * u2 + p;
                    bias[g * 2 + p] = bB_ih[row] + bB_hh[row];
                }
        }
    } else {
        const int loc = tid - 256;
        kc = loc & 3; u2 = loc >> 2;
        // L0: h-only chunks; reuse loader's hh path by passing kc+4
        load_pin_w8(nullptr, wA_hh, u2, kc + 4, false, wt);
        if (kc == 0) {
            #pragma unroll
            for (int g = 0; g < 4; ++g)
                #pragma unroll
                for (int p = 0; p < 2; ++p) {
                    const int row = g * H_ + 2 * u2 + p;
                    bias[g * 2 + p] = bA_ih[row] + bA_hh[row];
                    w0[g * 2 + p]   = wA_ih[row];
                }
        }
    }

    float c0 = 0.f, c1 = 0.f;
    float xt = (!isB) ? xA[(long)b * T_] : 0.f;

    // LDS init: A h[-1]=0 read at s=0 (parity 0); B h[-1]=0 read at s=1 (parity 1)
    if (isB) {
        if (tid < H_) xhB[1][(4 + (tid >> 4)) * 20 + (tid & 15)] = 0.f;
    } else {
        const int loc = tid - 256;
        if (loc < H_) xhA[0][(loc >> 4) * 20 + (loc & 15)] = 0.f;
    }
    block_sync_lds();

    for (int s = 0; s <= T_; ++s) {
        const int rb = s & 1, wb = rb ^ 1;

        if (isB) {
            if (s >= 1) {
                float acc[8];
                dot8(&xhB[rb][kc * 20], wt, acc);
                #pragma unroll
                for (int r = 0; r < 8; ++r) acc[r] = dpp_addf<0xB1>(acc[r]);
                #pragma unroll
                for (int r = 0; r < 8; ++r) acc[r] = dpp_addf<0x4E>(acc[r]);
                #pragma unroll
                for (int r = 0; r < 8; ++r) acc[r] = dpp_addf<0x141>(acc[r]);
                if (kc == 0) {
                    f32x2 hp = cell2(acc, bias, w0, 0.f, c0, c1);
                    const int u = 2 * u2;
                    *(f32x2*)&xhB[wb][(4 + (u >> 4)) * 20 + (u & 15)] = hp;
                    *(f32x2*)&hB_out[((long)b * T_ + (s - 1)) * H_ + u] = hp;
                }
            }
        } else {
            if (s < T_) {
                float xn = 0.f;
                if (s + 1 < T_) xn = xA[(long)b * T_ + s + 1];   // wave-uniform
                float acc[8];
                dot8(&xhA[rb][kc * 20], wt, acc);
                #pragma unroll
                for (int r = 0; r < 8; ++r) acc[r] = dpp_addf<0xB1>(acc[r]);
                #pragma unroll
                for (int r = 0; r < 8; ++r) acc[r] = dpp_addf<0x4E>(acc[r]);
                if (kc == 0) {
                    f32x2 hp = cell2(acc, bias, w0, xt, c0, c1);
                    const int u = 2 * u2;
                    *(f32x2*)&xhA[wb][(u >> 4) * 20 + (u & 15)] = hp;       // own h
                    *(f32x2*)&xhB[wb][(u >> 4) * 20 + (u & 15)] = hp;       // B's x
                }
                xt = xn;
            }
        }
        block_sync_lds();
    }
}

// ---------------------------------------------------------------------------
// K2: [L2 + L3 + L4] diagonal triple. Roles P/M/Z, 256 threads each (NCH=8
// over the 128-float [x|h]). In-place on buf: read row s+1 precedes overwrite
// of row s-2 by 3 barrier rounds (R8-validated).
// ---------------------------------------------------------------------------
__global__ __attribute__((amdgpu_flat_work_group_size(768, 768)))
void lstm_triple(const float* __restrict__ xin,   // [B,T,64] h_L1 (aliases hout)
                 float* __restrict__ hout,        // [B,T,64] h_L4
                 const float* __restrict__ wP_ih, const float* __restrict__ wP_hh,
                 const float* __restrict__ bP_ih, const float* __restrict__ bP_hh,
                 const float* __restrict__ wM_ih, const float* __restrict__ wM_hh,
                 const float* __restrict__ bM_ih, const float* __restrict__ bM_hh,
                 const float* __restrict__ wZ_ih, const float* __restrict__ wZ_hh,
                 const float* __restrict__ bZ_ih, const float* __restrict__ bZ_hh)
{
    const int b    = blockIdx.x;
    const int tid  = threadIdx.x;
    const int role = tid >> 8;      // 0=P(L2), 1=M(L3), 2=Z(L4); wave-uniform
    const int loc  = tid & 255;
    const int kc   = loc & 7;       // 16-float chunk of [x (0-3) | h (4-7)]
    const int u2   = loc >> 3;      // unit pair

    __shared__ __align__(16) float bufP[2][160];
    __shared__ __align__(16) float bufM[2][160];
    __shared__ __align__(16) float bufZ[2][160];

    const float* w_ih = (role == 0) ? wP_ih : (role == 1) ? wM_ih : wZ_ih;
    const float* w_hh = (role == 0) ? wP_hh : (role == 1) ? wM_hh : wZ_hh;
    const float* b_ih = (role == 0) ? bP_ih : (role == 1) ? bM_ih : bZ_ih;
    const float* b_hh = (role == 0) ? bP_hh : (role == 1) ? bM_hh : bZ_hh;
    float (*myBuf)[160] = (role == 0) ? bufP : (role == 1) ? bufM : bufZ;
    float (*dnBuf)[160] = (role == 0) ? bufM : (role == 1) ? bufZ : bufP; // Z's unused

    f32x4 wt[8][4];
    load_pin_w8(w_ih, w_hh, u2, kc, kc < 4, wt);

    float bias[8], w0[8];
    #pragma unroll
    for (int r = 0; r < 8; ++r) { bias[r] = 0.f; w0[r] = 0.f; }
    if (kc == 0) {
        #pragma unroll
        for (int g = 0; g < 4; ++g)
            #pragma unroll
            for (int p = 0; p < 2; ++p) {
                const int row = g * H_ + 2 * u2 + p;
                bias[g * 2 + p] = b_ih[row] + b_hh[row];
            }
    }
    float c0 = 0.f, c1 = 0.f;

    // LDS init: P reads parity 0 at s=0 (x row 0 + h=0); M parity 1 at s=1;
    // Z parity 0 at s=2.
    if (tid < H_) {
        const int u = tid;
        bufP[0][(u >> 4) * 20 + (u & 15)] = xin[(long)b * T_ * H_ + u];
        bufP[0][(4 + (u >> 4)) * 20 + (u & 15)] = 0.f;
    } else if (tid < 128) {
        const int u = tid - 64;
        bufM[1][(4 + (u >> 4)) * 20 + (u & 15)] = 0.f;
    } else if (tid < 192) {
        const int u = tid - 128;
        bufZ[0][(4 + (u >> 4)) * 20 + (u & 15)] = 0.f;
    }
    block_sync_lds();

    for (int s = 0; s <= T_ + 1; ++s) {
        const int rb = s & 1, wb = rb ^ 1;
        const bool active = (role == 0) ? (s < T_)
                          : (role == 1) ? (s >= 1 && s <= T_)
                                        : (s >= 2);
        if (active) {
            // P: prefetch next x row (kc==1 lanes, f32x2 each = 64 floats)
            f32x2 xn = {0.f, 0.f};
            if (role == 0 && kc == 1 && s + 1 < T_)
                xn = *(const f32x2*)&xin[((long)b * T_ + s + 1) * H_ + 2 * u2];

            float acc[8];
            dot8(&myBuf[rb][kc * 20], wt, acc);
            #pragma unroll
            for (int r = 0; r < 8; ++r) acc[r] = dpp_addf<0xB1>(acc[r]);
            #pragma unroll
            for (int r = 0; r < 8; ++r) acc[r] = dpp_addf<0x4E>(acc[r]);
            #pragma unroll
            for (int r = 0; r < 8; ++r) acc[r] = dpp_addf<0x141>(acc[r]);

            if (kc == 0) {
                f32x2 hp = cell2(acc, bias, w0, 0.f, c0, c1);
                const int u = 2 * u2;
                *(f32x2*)&myBuf[wb][(4 + (u >> 4)) * 20 + (u & 15)] = hp;   // own h
                if (role < 2)
                    *(f32x2*)&dnBuf[wb][(u >> 4) * 20 + (u & 15)] = hp;     // x of above
                else
                    *(f32x2*)&hout[((long)b * T_ + (s - 2)) * H_ + u] = hp;
            }
            if (role == 0 && kc == 1) {
                const int u = 2 * u2;
                *(f32x2*)&bufP[wb][(u >> 4) * 20 + (u & 15)] = xn;          // next x row
            }
        }
        block_sync_lds();
    }
}

// MLP head (R3-R9-validated): wave-uniform W1 -> scalar loads. ~25 us.
__global__ __launch_bounds__(256)
void mlp_head_v2(const float* __restrict__ hbuf,
                 const float* __restrict__ W1,
                 const float* __restrict__ b1,
                 const float* __restrict__ W2,
                 const float* __restrict__ b2,
                 float* __restrict__ out)
{
    const long r = (long)blockIdx.x * 256 + threadIdx.x;

    float row[H_];
    const float4* src = (const float4*)(hbuf + r * H_);
    #pragma unroll
    for (int q = 0; q < 16; ++q) {
        float4 v = src[q];
        row[4*q+0] = fmaxf(v.x, 0.f); row[4*q+1] = fmaxf(v.y, 0.f);
        row[4*q+2] = fmaxf(v.z, 0.f); row[4*q+3] = fmaxf(v.w, 0.f);
    }
    #pragma unroll
    for (int q = 0; q < 16; ++q)
        asm volatile("" : "+v"(row[4*q]), "+v"(row[4*q+1]),
                         "+v"(row[4*q+2]), "+v"(row[4*q+3]));

    float acc = b2[0];
    for (int jj = 0; jj < H_; ++jj) {
        const float* wrow = W1 + jj * H_;
        float s0 = 0.f, s1 = 0.f, s2 = 0.f, s3 = 0.f;
        #pragma unroll
        for (int q = 0; q < 16; ++q) {
            s0 += row[4*q+0] * wrow[4*q+0];
            s1 += row[4*q+1] * wrow[4*q+1];
            s2 += row[4*q+2] * wrow[4*q+2];
            s3 += row[4*q+3] * wrow[4*q+3];
        }
        float y = fmaxf(b1[jj] + (s0 + s1) + (s2 + s3), 0.f);
        acc += y * W2[jj];
    }
    out[r] = acc;
}

extern "C" void kernel_launch(void* const* d_in, const int* in_sizes, int n_in,
                              void* d_out, int out_size, void* d_ws, size_t ws_size,
                              hipStream_t stream) {
    const float* x     = (const float*)d_in[0];   // [B,T,1]
    const float* w_ih0 = (const float*)d_in[1];   // [256]
    const float* w_ihr = (const float*)d_in[2];   // [4,256,64]
    const float* w_hh  = (const float*)d_in[3];   // [5,256,64]
    const float* b_ih  = (const float*)d_in[4];   // [5,256]
    const float* b_hh  = (const float*)d_in[5];   // [5,256]
    const float* W1    = (const float*)d_in[6];   // [64,64]
    const float* b1    = (const float*)d_in[7];   // [64]
    const float* W2    = (const float*)d_in[8];   // [64]
    const float* b2    = (const float*)d_in[9];   // [1]
    // d_in[10] = future (0)

    float* out = (float*)d_out;
    float* buf = (float*)d_ws;                    // [B,T,64] fp32 = 64 MB

    const long LW = 4L * H_ * H_;   // 16384 floats per layer weight block
    const long LB = 4L * H_;        // 256 floats per layer bias block

    // K1: [L0 + L1] diagonal pair -> buf = h_L1
    lstm_pair01<<<dim3(B_), dim3(384), 0, stream>>>(
        x, buf,
        w_ih0,          w_hh + 0 * LW, b_ih + 0 * LB, b_hh + 0 * LB,
        w_ihr + 0 * LW, w_hh + 1 * LW, b_ih + 1 * LB, b_hh + 1 * LB);

    // K2: [L2 + L3 + L4] diagonal triple, in-place on buf -> buf = h_L4
    lstm_triple<<<dim3(B_), dim3(768), 0, stream>>>(
        buf, buf,
        w_ihr + 1 * LW, w_hh + 2 * LW, b_ih + 2 * LB, b_hh + 2 * LB,
        w_ihr + 2 * LW, w_hh + 3 * LW, b_ih + 3 * LB, b_hh + 3 * LB,
        w_ihr + 3 * LW, w_hh + 4 * LW, b_ih + 4 * LB, b_hh + 4 * LB);

    mlp_head_v2<<<dim3((B_ * T_) / 256), dim3(256), 0, stream>>>(
        buf, W1, b1, W2, b2, out);
}

// Round 11
// 2497.903 us; speedup vs baseline: 7.0551x; 1.2043x over previous
//
#include <hip/hip_runtime.h>

#define B_ 256
#define T_ 1024
#define H_ 64

typedef float f32x2 __attribute__((ext_vector_type(2)));
typedef float f32x4 __attribute__((ext_vector_type(4)));

// fast sigmoid/tanh via v_exp_f32 + v_rcp_f32 (validated R2-R10: absmax 0.0)
__device__ __forceinline__ float fast_sigmoid(float x) {
    float e = __builtin_amdgcn_exp2f(-1.4426950408889634f * x);
    return __builtin_amdgcn_rcpf(1.0f + e);
}
__device__ __forceinline__ float fast_tanh(float x) {
    float e = __builtin_amdgcn_exp2f(2.8853900817779268f * x);
    return 1.0f - 2.0f * __builtin_amdgcn_rcpf(1.0f + e);
}

// butterfly add via DPP: 0xB1=xor1, 0x4E=xor2, 0x141=half-mirror (=xor4 after 1,2)
template<int CTRL>
__device__ __forceinline__ float dpp_addf(float v) {
    int vi = __builtin_bit_cast(int, v);
    int sh = __builtin_amdgcn_update_dpp(0, vi, CTRL, 0xF, 0xF, true);
    return v + __builtin_bit_cast(float, sh);
}

// R8-validated: barrier draining LDS only (no vmcnt drain).
__device__ __forceinline__ void block_sync_lds() {
    asm volatile("s_waitcnt lgkmcnt(0)\n\ts_barrier" ::: "memory");
}

__device__ __forceinline__ f32x2 lo4(f32x4 v) { return __builtin_shufflevector(v, v, 0, 1); }
__device__ __forceinline__ f32x2 hi4(f32x4 v) { return __builtin_shufflevector(v, v, 2, 3); }
__device__ __forceinline__ float hsum4(f32x4 v) { return (v.x + v.y) + (v.z + v.w); }

// R6/R8-validated dot: 4 gate rows x 16 k
__device__ __forceinline__ void dot4x16(const f32x4 wt[4][4],
                                        f32x4 h0, f32x4 h1, f32x4 h2, f32x4 h3,
                                        float acc[4]) {
    #pragma unroll
    for (int r = 0; r < 4; ++r) {
        f32x2 a = {0.f, 0.f}, d = {0.f, 0.f};
        a = __builtin_elementwise_fma(lo4(wt[r][0]), lo4(h0), a);
        d = __builtin_elementwise_fma(hi4(wt[r][0]), hi4(h0), d);
        a = __builtin_elementwise_fma(lo4(wt[r][1]), lo4(h1), a);
        d = __builtin_elementwise_fma(hi4(wt[r][1]), hi4(h1), d);
        a = __builtin_elementwise_fma(lo4(wt[r][2]), lo4(h2), a);
        d = __builtin_elementwise_fma(hi4(wt[r][2]), hi4(h2), d);
        a = __builtin_elementwise_fma(lo4(wt[r][3]), lo4(h3), a);
        d = __builtin_elementwise_fma(hi4(wt[r][3]), hi4(h3), d);
        f32x2 s = a + d;
        acc[r] = s.x + s.y;
    }
}

// ---------------------------------------------------------------------------
// K1: diagonal pair [L0+L1] — R8's measured-620us kernel VERBATIM.
// ---------------------------------------------------------------------------
__global__ __attribute__((amdgpu_flat_work_group_size(768, 768)))
void lstm_pair01(const float* __restrict__ xA,     // [B,T] scalar input
                 float* __restrict__ hB_out,       // [B,T,64] = h_L1
                 const float* __restrict__ wA_ih,  // [256]
                 const float* __restrict__ wA_hh,  // [256,64]
                 const float* __restrict__ bA_ih,
                 const float* __restrict__ bA_hh,
                 const float* __restrict__ wB_ih,  // [256,64]
                 const float* __restrict__ wB_hh,  // [256,64]
                 const float* __restrict__ bB_ih,
                 const float* __restrict__ bB_hh)
{
    const int b   = blockIdx.x;
    const int tid = threadIdx.x;
    const bool isB = (tid < 512);

    __shared__ __align__(16) float xhA[2][80];    // A: h chunks (4x16 padded to 20)
    __shared__ __align__(16) float xhB[2][160];   // B: [h_A | h_B] chunks

    int kc, j;
    f32x4 wt[4][4];
    float bias0 = 0.f, bias1 = 0.f, bias2 = 0.f, bias3 = 0.f;
    float w00 = 0.f, w01 = 0.f, w02 = 0.f, w03 = 0.f;

    if (isB) {
        kc = tid & 7; j = tid >> 3;
        #pragma unroll
        for (int r = 0; r < 4; ++r) {
            const int row = r * H_ + j;
            const float* base = (kc < 4) ? (wB_ih + row * H_ + kc * 16)
                                         : (wB_hh + row * H_ + (kc - 4) * 16);
            #pragma unroll
            for (int q = 0; q < 4; ++q) wt[r][q] = *(const f32x4*)(base + 4 * q);
        }
        if (kc == 0) {
            bias0 = bB_ih[0*H_+j] + bB_hh[0*H_+j];
            bias1 = bB_ih[1*H_+j] + bB_hh[1*H_+j];
            bias2 = bB_ih[2*H_+j] + bB_hh[2*H_+j];
            bias3 = bB_ih[3*H_+j] + bB_hh[3*H_+j];
        }
    } else {
        const int t2 = tid - 512;
        kc = t2 & 3; j = t2 >> 2;
        #pragma unroll
        for (int r = 0; r < 4; ++r) {
            const int row = r * H_ + j;
            const float* base = wA_hh + row * H_ + kc * 16;
            #pragma unroll
            for (int q = 0; q < 4; ++q) wt[r][q] = *(const f32x4*)(base + 4 * q);
        }
        if (kc == 0) {
            bias0 = bA_ih[0*H_+j] + bA_hh[0*H_+j];
            bias1 = bA_ih[1*H_+j] + bA_hh[1*H_+j];
            bias2 = bA_ih[2*H_+j] + bA_hh[2*H_+j];
            bias3 = bA_ih[3*H_+j] + bA_hh[3*H_+j];
            w00 = wA_ih[0*H_+j]; w01 = wA_ih[1*H_+j];
            w02 = wA_ih[2*H_+j]; w03 = wA_ih[3*H_+j];
        }
    }
    #pragma unroll
    for (int r = 0; r < 4; ++r)
        #pragma unroll
        for (int q = 0; q < 4; ++q)
            asm volatile("" : "+v"(wt[r][q]));

    float c_st = 0.f;
    float xt = (!isB) ? xA[(long)b * T_] : 0.f;

    if (isB) {
        if (tid < H_) xhB[1][80 + (tid >> 4) * 20 + (tid & 15)] = 0.f;  // h_B[-1]=0
    } else {
        const int t2 = tid - 512;
        if (t2 < H_) xhA[0][(t2 >> 4) * 20 + (t2 & 15)] = 0.f;          // h_A[-1]=0
    }
    block_sync_lds();

    for (int s = 0; s <= T_; ++s) {
        const int rb = s & 1, wb = rb ^ 1;

        if (isB) {
            if (s >= 1) {
                const f32x4* xv = (const f32x4*)&xhB[rb][kc * 20];
                f32x4 h0 = xv[0], h1 = xv[1], h2 = xv[2], h3 = xv[3];
                float acc[4];
                dot4x16(wt, h0, h1, h2, h3, acc);
                acc[0] = dpp_addf<0xB1>(acc[0]); acc[1] = dpp_addf<0xB1>(acc[1]);
                acc[2] = dpp_addf<0xB1>(acc[2]); acc[3] = dpp_addf<0xB1>(acc[3]);
                acc[0] = dpp_addf<0x4E>(acc[0]); acc[1] = dpp_addf<0x4E>(acc[1]);
                acc[2] = dpp_addf<0x4E>(acc[2]); acc[3] = dpp_addf<0x4E>(acc[3]);
                acc[0] = dpp_addf<0x141>(acc[0]); acc[1] = dpp_addf<0x141>(acc[1]);
                acc[2] = dpp_addf<0x141>(acc[2]); acc[3] = dpp_addf<0x141>(acc[3]);
                if (kc == 0) {
                    float i_ = fast_sigmoid(acc[0] + bias0);
                    float f_ = fast_sigmoid(acc[1] + bias1);
                    float g_ = fast_tanh   (acc[2] + bias2);
                    float o_ = fast_sigmoid(acc[3] + bias3);
                    c_st = f_ * c_st + i_ * g_;
                    float h = o_ * fast_tanh(c_st);
                    xhB[wb][80 + (j >> 4) * 20 + (j & 15)] = h;
                    hB_out[((long)b * T_ + (s - 1)) * H_ + j] = h;
                }
            }
        } else {
            if (s < T_) {
                float xn = 0.f;
                if (s + 1 < T_) xn = xA[(long)b * T_ + s + 1];   // wave-uniform
                const f32x4* xv = (const f32x4*)&xhA[rb][kc * 20];
                f32x4 h0 = xv[0], h1 = xv[1], h2 = xv[2], h3 = xv[3];
                float acc[4];
                dot4x16(wt, h0, h1, h2, h3, acc);
                acc[0] = dpp_addf<0xB1>(acc[0]); acc[1] = dpp_addf<0xB1>(acc[1]);
                acc[2] = dpp_addf<0xB1>(acc[2]); acc[3] = dpp_addf<0xB1>(acc[3]);
                acc[0] = dpp_addf<0x4E>(acc[0]); acc[1] = dpp_addf<0x4E>(acc[1]);
                acc[2] = dpp_addf<0x4E>(acc[2]); acc[3] = dpp_addf<0x4E>(acc[3]);
                if (kc == 0) {
                    float gi = acc[0] + bias0 + w00 * xt;
                    float gf = acc[1] + bias1 + w01 * xt;
                    float gg = acc[2] + bias2 + w02 * xt;
                    float go = acc[3] + bias3 + w03 * xt;
                    float i_ = fast_sigmoid(gi);
                    float f_ = fast_sigmoid(gf);
                    float g_ = fast_tanh(gg);
                    float o_ = fast_sigmoid(go);
                    c_st = f_ * c_st + i_ * g_;
                    float h = o_ * fast_tanh(c_st);
                    const int off = (j >> 4) * 20 + (j & 15);
                    xhA[wb][off] = h;
                    xhB[wb][off] = h;                      // feed B's x-slot
                }
                xt = xn;
            }
        }
        block_sync_lds();
    }
}

// ---------------------------------------------------------------------------
// K2: diagonal TRIPLE [L2+L3+L4], R11 geometry: thread owns 8 gate rows
// (4 gates x 2 units) x one 16-float k-chunk (kc in [0,8) over [x|h]).
// 128 pinned weight floats; LDS reads HALVED vs R8 (4 b128/thread).
// TWO-PASS dot reuses 4 f32x4 accumulators (rows 0-3 then 4-7) to keep the
// arch-VGPR live set at R8's proven-safe size (R10's a[8] caused the
// AGPR-copy storm). Chunk kc at kc*20 floats -> 8 addresses on disjoint bank
// quads (conflict-free, R4/R10-validated). One barrier/step (lgkm-only).
// In-place on buf: P prefetches row s+1, Z overwrites row s-2 (3-round gap).
// ---------------------------------------------------------------------------
__global__ __attribute__((amdgpu_flat_work_group_size(768, 768)))
void lstm_triple(const float* __restrict__ xin,   // [B,T,64] h_L1 (aliases hout)
                 float* __restrict__ hout,        // [B,T,64] h_L4
                 const float* __restrict__ wP_ih, const float* __restrict__ wP_hh,
                 const float* __restrict__ bP_ih, const float* __restrict__ bP_hh,
                 const float* __restrict__ wM_ih, const float* __restrict__ wM_hh,
                 const float* __restrict__ bM_ih, const float* __restrict__ bM_hh,
                 const float* __restrict__ wZ_ih, const float* __restrict__ wZ_hh,
                 const float* __restrict__ bZ_ih, const float* __restrict__ bZ_hh)
{
    const int b    = blockIdx.x;
    const int tid  = threadIdx.x;
    const int role = tid >> 8;      // 0=P(L2), 1=M(L3), 2=Z(L4); wave-uniform
    const int loc  = tid & 255;
    const int kc   = loc & 7;       // 16-float chunk: 0-3 = x, 4-7 = h
    const int u2   = loc >> 3;      // unit pair: units 2*u2, 2*u2+1

    __shared__ __align__(16) float bufP[2][160];
    __shared__ __align__(16) float bufM[2][160];
    __shared__ __align__(16) float bufZ[2][160];

    const float* w_ih = (role == 0) ? wP_ih : (role == 1) ? wM_ih : wZ_ih;
    const float* w_hh = (role == 0) ? wP_hh : (role == 1) ? wM_hh : wZ_hh;
    const float* b_ih = (role == 0) ? bP_ih : (role == 1) ? bM_ih : bZ_ih;
    const float* b_hh = (role == 0) ? bP_hh : (role == 1) ? bM_hh : bZ_hh;
    float (*myBuf)[160] = (role == 0) ? bufP : (role == 1) ? bufM : bufZ;
    float (*dnBuf)[160] = (role == 0) ? bufM : (role == 1) ? bufZ : bufP; // Z's unused

    // ---- weights: 8 rows x 16-k chunk, pinned (128 floats -> AGPR-resident) ----
    // row r = g*64 + 2*u2 + p, r index = g*2+p (r0,r1=i; r2,r3=f; r4,r5=g; r6,r7=o)
    f32x4 wtA[4][4], wtB[4][4];   // rows 0-3 / rows 4-7
    #pragma unroll
    for (int g = 0; g < 2; ++g)
        #pragma unroll
        for (int p = 0; p < 2; ++p) {
            const int row = g * H_ + 2 * u2 + p;
            const float* base = (kc < 4) ? (w_ih + row * H_ + kc * 16)
                                         : (w_hh + row * H_ + (kc - 4) * 16);
            #pragma unroll
            for (int q = 0; q < 4; ++q)
                wtA[g * 2 + p][q] = *(const f32x4*)(base + 4 * q);
        }
    #pragma unroll
    for (int g = 2; g < 4; ++g)
        #pragma unroll
        for (int p = 0; p < 2; ++p) {
            const int row = g * H_ + 2 * u2 + p;
            const float* base = (kc < 4) ? (w_ih + row * H_ + kc * 16)
                                         : (w_hh + row * H_ + (kc - 4) * 16);
            #pragma unroll
            for (int q = 0; q < 4; ++q)
                wtB[(g - 2) * 2 + p][q] = *(const f32x4*)(base + 4 * q);
        }
    #pragma unroll
    for (int r = 0; r < 4; ++r)
        #pragma unroll
        for (int q = 0; q < 4; ++q) {
            asm volatile("" : "+v"(wtA[r][q]));
            asm volatile("" : "+v"(wtB[r][q]));
        }

    float bias[8];
    #pragma unroll
    for (int r = 0; r < 8; ++r) bias[r] = 0.f;
    if (kc == 0) {
        #pragma unroll
        for (int g = 0; g < 4; ++g)
            #pragma unroll
            for (int p = 0; p < 2; ++p) {
                const int row = g * H_ + 2 * u2 + p;
                bias[g * 2 + p] = b_ih[row] + b_hh[row];
            }
    }
    float c0 = 0.f, c1 = 0.f;

    // LDS init: P reads parity 0 at s=0 (x row 0 + h=0); M parity 1; Z parity 0.
    if (tid < H_) {
        const int u = tid;
        bufP[0][(u >> 4) * 20 + (u & 15)] = xin[(long)b * T_ * H_ + u];
        bufP[0][(4 + (u >> 4)) * 20 + (u & 15)] = 0.f;
    } else if (tid < 128) {
        const int u = tid - 64;
        bufM[1][(4 + (u >> 4)) * 20 + (u & 15)] = 0.f;
    } else if (tid < 192) {
        const int u = tid - 128;
        bufZ[0][(4 + (u >> 4)) * 20 + (u & 15)] = 0.f;
    }
    block_sync_lds();

    for (int s = 0; s <= T_ + 1; ++s) {
        const int rb = s & 1, wb = rb ^ 1;
        const bool active = (role == 0) ? (s < T_)
                          : (role == 1) ? (s >= 1 && s <= T_)
                                        : (s >= 2);
        if (active) {
            // P: prefetch next x row (kc==1 lanes, f32x2 per unit pair)
            f32x2 xn = {0.f, 0.f};
            if (role == 0 && kc == 1 && s + 1 < T_)
                xn = *(const f32x2*)&xin[((long)b * T_ + s + 1) * H_ + 2 * u2];

            // ---- ingest chunk kc: 4 conflict-free ds_read_b128 ----
            const f32x4* xv = (const f32x4*)&myBuf[rb][kc * 20];
            f32x4 ch0 = xv[0], ch1 = xv[1], ch2 = xv[2], ch3 = xv[3];

            float red[8];
            // pass 1: rows 0-3 (i,f gates)
            {
                f32x4 a0 = {0,0,0,0}, a1 = {0,0,0,0}, a2 = {0,0,0,0}, a3 = {0,0,0,0};
                a0 = __builtin_elementwise_fma(wtA[0][0], ch0, a0);
                a1 = __builtin_elementwise_fma(wtA[1][0], ch0, a1);
                a2 = __builtin_elementwise_fma(wtA[2][0], ch0, a2);
                a3 = __builtin_elementwise_fma(wtA[3][0], ch0, a3);
                a0 = __builtin_elementwise_fma(wtA[0][1], ch1, a0);
                a1 = __builtin_elementwise_fma(wtA[1][1], ch1, a1);
                a2 = __builtin_elementwise_fma(wtA[2][1], ch1, a2);
                a3 = __builtin_elementwise_fma(wtA[3][1], ch1, a3);
                a0 = __builtin_elementwise_fma(wtA[0][2], ch2, a0);
                a1 = __builtin_elementwise_fma(wtA[1][2], ch2, a1);
                a2 = __builtin_elementwise_fma(wtA[2][2], ch2, a2);
                a3 = __builtin_elementwise_fma(wtA[3][2], ch2, a3);
                a0 = __builtin_elementwise_fma(wtA[0][3], ch3, a0);
                a1 = __builtin_elementwise_fma(wtA[1][3], ch3, a1);
                a2 = __builtin_elementwise_fma(wtA[2][3], ch3, a2);
                a3 = __builtin_elementwise_fma(wtA[3][3], ch3, a3);
                red[0] = hsum4(a0); red[1] = hsum4(a1);
                red[2] = hsum4(a2); red[3] = hsum4(a3);
            }
            // pass 2: rows 4-7 (g,o gates) — reuses the accumulator registers
            {
                f32x4 a0 = {0,0,0,0}, a1 = {0,0,0,0}, a2 = {0,0,0,0}, a3 = {0,0,0,0};
                a0 = __builtin_elementwise_fma(wtB[0][0], ch0, a0);
                a1 = __builtin_elementwise_fma(wtB[1][0], ch0, a1);
                a2 = __builtin_elementwise_fma(wtB[2][0], ch0, a2);
                a3 = __builtin_elementwise_fma(wtB[3][0], ch0, a3);
                a0 = __builtin_elementwise_fma(wtB[0][1], ch1, a0);
                a1 = __builtin_elementwise_fma(wtB[1][1], ch1, a1);
                a2 = __builtin_elementwise_fma(wtB[2][1], ch1, a2);
                a3 = __builtin_elementwise_fma(wtB[3][1], ch1, a3);
                a0 = __builtin_elementwise_fma(wtB[0][2], ch2, a0);
                a1 = __builtin_elementwise_fma(wtB[1][2], ch2, a1);
                a2 = __builtin_elementwise_fma(wtB[2][2], ch2, a2);
                a3 = __builtin_elementwise_fma(wtB[3][2], ch2, a3);
                a0 = __builtin_elementwise_fma(wtB[0][3], ch3, a0);
                a1 = __builtin_elementwise_fma(wtB[1][3], ch3, a1);
                a2 = __builtin_elementwise_fma(wtB[2][3], ch3, a2);
                a3 = __builtin_elementwise_fma(wtB[3][3], ch3, a3);
                red[4] = hsum4(a0); red[5] = hsum4(a1);
                red[6] = hsum4(a2); red[7] = hsum4(a3);
            }

            // ---- DPP all-reduce over 8 kc lanes (3 stages, R3/R8-validated) ----
            #pragma unroll
            for (int r = 0; r < 8; ++r) red[r] = dpp_addf<0xB1>(red[r]);
            #pragma unroll
            for (int r = 0; r < 8; ++r) red[r] = dpp_addf<0x4E>(red[r]);
            #pragma unroll
            for (int r = 0; r < 8; ++r) red[r] = dpp_addf<0x141>(red[r]);

            // ---- cell update: 2 units on kc==0 lanes ----
            if (kc == 0) {
                float h0v, h1v;
                {
                    float i_ = fast_sigmoid(red[0] + bias[0]);
                    float f_ = fast_sigmoid(red[2] + bias[2]);
                    float g_ = fast_tanh   (red[4] + bias[4]);
                    float o_ = fast_sigmoid(red[6] + bias[6]);
                    c0 = f_ * c0 + i_ * g_;
                    h0v = o_ * fast_tanh(c0);
                }
                {
                    float i_ = fast_sigmoid(red[1] + bias[1]);
                    float f_ = fast_sigmoid(red[3] + bias[3]);
                    float g_ = fast_tanh   (red[5] + bias[5]);
                    float o_ = fast_sigmoid(red[7] + bias[7]);
                    c1 = f_ * c1 + i_ * g_;
                    h1v = o_ * fast_tanh(c1);
                }
                const int u = 2 * u2;
                const f32x2 hp = {h0v, h1v};
                *(f32x2*)&myBuf[wb][(4 + (u >> 4)) * 20 + (u & 15)] = hp;   // own h
                if (role < 2)
                    *(f32x2*)&dnBuf[wb][(u >> 4) * 20 + (u & 15)] = hp;     // x of above
                else
                    *(f32x2*)&hout[((long)b * T_ + (s - 2)) * H_ + u] = hp;
            }
            if (role == 0 && kc == 1) {
                const int u = 2 * u2;
                *(f32x2*)&bufP[wb][(u >> 4) * 20 + (u & 15)] = xn;          // next x row
            }
        }
        block_sync_lds();
    }
}

// MLP head (R3-R10-validated): wave-uniform W1 -> scalar loads. ~25 us.
__global__ __launch_bounds__(256)
void mlp_head_v2(const float* __restrict__ hbuf,
                 const float* __restrict__ W1,
                 const float* __restrict__ b1,
                 const float* __restrict__ W2,
                 const float* __restrict__ b2,
                 float* __restrict__ out)
{
    const long r = (long)blockIdx.x * 256 + threadIdx.x;

    float row[H_];
    const float4* src = (const float4*)(hbuf + r * H_);
    #pragma unroll
    for (int q = 0; q < 16; ++q) {
        float4 v = src[q];
        row[4*q+0] = fmaxf(v.x, 0.f); row[4*q+1] = fmaxf(v.y, 0.f);
        row[4*q+2] = fmaxf(v.z, 0.f); row[4*q+3] = fmaxf(v.w, 0.f);
    }
    #pragma unroll
    for (int q = 0; q < 16; ++q)
        asm volatile("" : "+v"(row[4*q]), "+v"(row[4*q+1]),
                         "+v"(row[4*q+2]), "+v"(row[4*q+3]));

    float acc = b2[0];
    for (int jj = 0; jj < H_; ++jj) {
        const float* wrow = W1 + jj * H_;
        float s0 = 0.f, s1 = 0.f, s2 = 0.f, s3 = 0.f;
        #pragma unroll
        for (int q = 0; q < 16; ++q) {
            s0 += row[4*q+0] * wrow[4*q+0];
            s1 += row[4*q+1] * wrow[4*q+1];
            s2 += row[4*q+2] * wrow[4*q+2];
            s3 += row[4*q+3] * wrow[4*q+3];
        }
        float y = fmaxf(b1[jj] + (s0 + s1) + (s2 + s3), 0.f);
        acc += y * W2[jj];
    }
    out[r] = acc;
}

extern "C" void kernel_launch(void* const* d_in, const int* in_sizes, int n_in,
                              void* d_out, int out_size, void* d_ws, size_t ws_size,
                              hipStream_t stream) {
    const float* x     = (const float*)d_in[0];   // [B,T,1]
    const float* w_ih0 = (const float*)d_in[1];   // [256]
    const float* w_ihr = (const float*)d_in[2];   // [4,256,64]
    const float* w_hh  = (const float*)d_in[3];   // [5,256,64]
    const float* b_ih  = (const float*)d_in[4];   // [5,256]
    const float* b_hh  = (const float*)d_in[5];   // [5,256]
    const float* W1    = (const float*)d_in[6];   // [64,64]
    const float* b1    = (const float*)d_in[7];   // [64]
    const float* W2    = (const float*)d_in[8];   // [64]
    const float* b2    = (const float*)d_in[9];   // [1]
    // d_in[10] = future (0)

    float* out = (float*)d_out;
    float* buf = (float*)d_ws;                    // [B,T,64] fp32 = 64 MB

    const long LW = 4L * H_ * H_;   // 16384 floats per layer weight block
    const long LB = 4L * H_;        // 256 floats per layer bias block

    // K1: [L0 + L1] diagonal pair -> buf = h_L1
    lstm_pair01<<<dim3(B_), dim3(768), 0, stream>>>(
        x, buf,
        w_ih0,          w_hh + 0 * LW, b_ih + 0 * LB, b_hh + 0 * LB,
        w_ihr + 0 * LW, w_hh + 1 * LW, b_ih + 1 * LB, b_hh + 1 * LB);

    // K2: [L2 + L3 + L4] diagonal triple, in-place on buf -> buf = h_L4
    lstm_triple<<<dim3(B_), dim3(768), 0, stream>>>(
        buf, buf,
        w_ihr + 1 * LW, w_hh + 2 * LW, b_ih + 2 * LB, b_hh + 2 * LB,
        w_ihr + 2 * LW, w_hh + 3 * LW, b_ih + 3 * LB, b_hh + 3 * LB,
        w_ihr + 3 * LW, w_hh + 4 * LW, b_ih + 4 * LB, b_hh + 4 * LB);

    mlp_head_v2<<<dim3((B_ * T_) / 256), dim3(256), 0, stream>>>(
        buf, W1, b1, W2, b2, out);
}

// Round 12
// 1717.028 us; speedup vs baseline: 10.2636x; 1.4548x over previous
//
#include <hip/hip_runtime.h>

#define B_ 256
#define T_ 1024
#define H_ 64

typedef float f32x2 __attribute__((ext_vector_type(2)));
typedef float f32x4 __attribute__((ext_vector_type(4)));

// fast sigmoid/tanh via v_exp_f32 + v_rcp_f32 (validated R2-R11: absmax 0.0)
__device__ __forceinline__ float fast_sigmoid(float x) {
    float e = __builtin_amdgcn_exp2f(-1.4426950408889634f * x);
    return __builtin_amdgcn_rcpf(1.0f + e);
}
__device__ __forceinline__ float fast_tanh(float x) {
    float e = __builtin_amdgcn_exp2f(2.8853900817779268f * x);
    return 1.0f - 2.0f * __builtin_amdgcn_rcpf(1.0f + e);
}

// butterfly add via DPP: 0xB1=xor1, 0x4E=xor2 (NCH=4 -> 2 stages, R8-validated)
template<int CTRL>
__device__ __forceinline__ float dpp_addf(float v) {
    int vi = __builtin_bit_cast(int, v);
    int sh = __builtin_amdgcn_update_dpp(0, vi, CTRL, 0xF, 0xF, true);
    return v + __builtin_bit_cast(float, sh);
}

// R8-validated: barrier draining LDS only (no vmcnt drain).
__device__ __forceinline__ void block_sync_lds() {
    asm volatile("s_waitcnt lgkmcnt(0)\n\ts_barrier" ::: "memory");
}

__device__ __forceinline__ float hsum4(f32x4 v) { return (v.x + v.y) + (v.z + v.w); }

// ---- heavy role building blocks (R8-triple-validated geometry) ----
// thread = (j in [0,64), kc in [0,4)): 4 gate rows {r*64+j} x 32-float chunk
// of [x(0..63) | h(64..127)]; chunk kc at kc*36 floats (conflict-free b128).
__device__ __forceinline__ void load_w_heavy(const float* __restrict__ w_ih,
                                             const float* __restrict__ w_hh,
                                             int j, int kc, f32x4 wt[4][8]) {
    #pragma unroll
    for (int r = 0; r < 4; ++r) {
        const int row = r * H_ + j;
        const float* base = (kc < 2) ? (w_ih + row * H_ + kc * 32)
                                     : (w_hh + row * H_ + (kc - 2) * 32);
        #pragma unroll
        for (int q = 0; q < 8; ++q)
            wt[r][q] = *(const f32x4*)(base + 4 * q);
    }
    #pragma unroll
    for (int r = 0; r < 4; ++r)
        #pragma unroll
        for (int q = 0; q < 8; ++q)
            asm volatile("" : "+v"(wt[r][q]));
}

__device__ __forceinline__ void dot4x32(const float* chunk, const f32x4 wt[4][8],
                                        float acc[4]) {
    const f32x4* xv = (const f32x4*)chunk;
    f32x4 a0 = {0,0,0,0}, a1 = {0,0,0,0}, a2 = {0,0,0,0}, a3 = {0,0,0,0};
    #pragma unroll
    for (int q = 0; q < 8; ++q) {
        f32x4 hq = xv[q];
        a0 = __builtin_elementwise_fma(wt[0][q], hq, a0);
        a1 = __builtin_elementwise_fma(wt[1][q], hq, a1);
        a2 = __builtin_elementwise_fma(wt[2][q], hq, a2);
        a3 = __builtin_elementwise_fma(wt[3][q], hq, a3);
    }
    acc[0] = hsum4(a0); acc[1] = hsum4(a1);
    acc[2] = hsum4(a2); acc[3] = hsum4(a3);
}

// ---------------------------------------------------------------------------
// K1': diagonal TRIPLE [L0+L1+L2]. role 0 = L0 (light: h-only 16-float
// chunks, scalar-x term), roles 1,2 = heavy. L0 t=s, L1 t=s-1, L2 t=s-2.
// h flows role->role through LDS; L2 writes global h_L2.
// ---------------------------------------------------------------------------
__global__ __attribute__((amdgpu_flat_work_group_size(768, 768)))
void lstm_tri012(const float* __restrict__ x,      // [B,T]
                 float* __restrict__ hout,         // [B,T,64] = h_L2
                 const float* __restrict__ w_ih0,  // [256]
                 const float* __restrict__ whh0,
                 const float* __restrict__ bih0, const float* __restrict__ bhh0,
                 const float* __restrict__ wih1, const float* __restrict__ whh1,
                 const float* __restrict__ bih1, const float* __restrict__ bhh1,
                 const float* __restrict__ wih2, const float* __restrict__ whh2,
                 const float* __restrict__ bih2, const float* __restrict__ bhh2)
{
    const int b    = blockIdx.x;
    const int tid  = threadIdx.x;
    const int role = tid >> 8;      // 0=L0, 1=L1, 2=L2 (wave-uniform)
    const int loc  = tid & 255;
    const int kc   = loc & 3;
    const int j    = loc >> 2;      // hidden unit

    __shared__ __align__(16) float bufL0[2][80];    // L0 h: 4 chunks x 20
    __shared__ __align__(16) float bufL1[2][144];   // [x|h]: 4 chunks x 36
    __shared__ __align__(16) float bufL2[2][144];

    f32x4 wt[4][8];                 // L0 uses [4][4] portion
    float bias0 = 0.f, bias1 = 0.f, bias2 = 0.f, bias3 = 0.f;
    float w00 = 0.f, w01 = 0.f, w02 = 0.f, w03 = 0.f;

    if (role == 0) {
        #pragma unroll
        for (int r = 0; r < 4; ++r) {
            const int row = r * H_ + j;
            const float* base = whh0 + row * H_ + kc * 16;
            #pragma unroll
            for (int q = 0; q < 4; ++q)
                wt[r][q] = *(const f32x4*)(base + 4 * q);
        }
        #pragma unroll
        for (int r = 0; r < 4; ++r)
            #pragma unroll
            for (int q = 0; q < 4; ++q)
                asm volatile("" : "+v"(wt[r][q]));
        if (kc == 0) {
            bias0 = bih0[0*H_+j] + bhh0[0*H_+j];
            bias1 = bih0[1*H_+j] + bhh0[1*H_+j];
            bias2 = bih0[2*H_+j] + bhh0[2*H_+j];
            bias3 = bih0[3*H_+j] + bhh0[3*H_+j];
            w00 = w_ih0[0*H_+j]; w01 = w_ih0[1*H_+j];
            w02 = w_ih0[2*H_+j]; w03 = w_ih0[3*H_+j];
        }
    } else {
        const float* wih = (role == 1) ? wih1 : wih2;
        const float* whh = (role == 1) ? whh1 : whh2;
        const float* bih = (role == 1) ? bih1 : bih2;
        const float* bhh = (role == 1) ? bhh1 : bhh2;
        load_w_heavy(wih, whh, j, kc, wt);
        if (kc == 0) {
            bias0 = bih[0*H_+j] + bhh[0*H_+j];
            bias1 = bih[1*H_+j] + bhh[1*H_+j];
            bias2 = bih[2*H_+j] + bhh[2*H_+j];
            bias3 = bih[3*H_+j] + bhh[3*H_+j];
        }
    }
    float c_st = 0.f;
    float xt = (role == 0) ? x[(long)b * T_] : 0.f;

    float (*myBuf)[144] = (role == 1) ? bufL1 : bufL2;

    // LDS init: L0 reads parity 0 at s=0; L1 parity 1 at s=1; L2 parity 0 at s=2.
    if (loc < H_) {
        const int u = loc;
        if (role == 0)      bufL0[0][(u >> 4) * 20 + (u & 15)] = 0.f;         // h_L0[-1]
        else if (role == 1) bufL1[1][(2 + (u >> 5)) * 36 + (u & 31)] = 0.f;   // h_L1[-1]
        else                bufL2[0][(2 + (u >> 5)) * 36 + (u & 31)] = 0.f;   // h_L2[-1]
    }
    block_sync_lds();

    for (int s = 0; s <= T_ + 1; ++s) {
        const int rb = s & 1, wb = rb ^ 1;
        const bool active = (role == 0) ? (s < T_)
                          : (role == 1) ? (s >= 1 && s <= T_)
                                        : (s >= 2);
        if (active) {
            if (role == 0) {
                float xn = 0.f;
                if (s + 1 < T_) xn = x[(long)b * T_ + s + 1];   // wave-uniform
                const f32x4* xv = (const f32x4*)&bufL0[rb][kc * 20];
                f32x4 h0 = xv[0], h1 = xv[1], h2 = xv[2], h3 = xv[3];
                f32x4 a0 = {0,0,0,0}, a1 = {0,0,0,0}, a2 = {0,0,0,0}, a3 = {0,0,0,0};
                a0 = __builtin_elementwise_fma(wt[0][0], h0, a0);
                a1 = __builtin_elementwise_fma(wt[1][0], h0, a1);
                a2 = __builtin_elementwise_fma(wt[2][0], h0, a2);
                a3 = __builtin_elementwise_fma(wt[3][0], h0, a3);
                a0 = __builtin_elementwise_fma(wt[0][1], h1, a0);
                a1 = __builtin_elementwise_fma(wt[1][1], h1, a1);
                a2 = __builtin_elementwise_fma(wt[2][1], h1, a2);
                a3 = __builtin_elementwise_fma(wt[3][1], h1, a3);
                a0 = __builtin_elementwise_fma(wt[0][2], h2, a0);
                a1 = __builtin_elementwise_fma(wt[1][2], h2, a1);
                a2 = __builtin_elementwise_fma(wt[2][2], h2, a2);
                a3 = __builtin_elementwise_fma(wt[3][2], h2, a3);
                a0 = __builtin_elementwise_fma(wt[0][3], h3, a0);
                a1 = __builtin_elementwise_fma(wt[1][3], h3, a1);
                a2 = __builtin_elementwise_fma(wt[2][3], h3, a2);
                a3 = __builtin_elementwise_fma(wt[3][3], h3, a3);
                float acc0 = hsum4(a0), acc1 = hsum4(a1);
                float acc2 = hsum4(a2), acc3 = hsum4(a3);
                acc0 = dpp_addf<0xB1>(acc0); acc1 = dpp_addf<0xB1>(acc1);
                acc2 = dpp_addf<0xB1>(acc2); acc3 = dpp_addf<0xB1>(acc3);
                acc0 = dpp_addf<0x4E>(acc0); acc1 = dpp_addf<0x4E>(acc1);
                acc2 = dpp_addf<0x4E>(acc2); acc3 = dpp_addf<0x4E>(acc3);
                if (kc == 0) {
                    float i_ = fast_sigmoid(acc0 + bias0 + w00 * xt);
                    float f_ = fast_sigmoid(acc1 + bias1 + w01 * xt);
                    float g_ = fast_tanh   (acc2 + bias2 + w02 * xt);
                    float o_ = fast_sigmoid(acc3 + bias3 + w03 * xt);
                    c_st = f_ * c_st + i_ * g_;
                    float h = o_ * fast_tanh(c_st);
                    bufL0[wb][(j >> 4) * 20 + (j & 15)] = h;            // own h
                    bufL1[wb][(j >> 5) * 36 + (j & 31)] = h;            // L1's x
                }
                xt = xn;
            } else {
                float acc[4];
                dot4x32(&myBuf[rb][kc * 36], wt, acc);
                acc[0] = dpp_addf<0xB1>(acc[0]); acc[1] = dpp_addf<0xB1>(acc[1]);
                acc[2] = dpp_addf<0xB1>(acc[2]); acc[3] = dpp_addf<0xB1>(acc[3]);
                acc[0] = dpp_addf<0x4E>(acc[0]); acc[1] = dpp_addf<0x4E>(acc[1]);
                acc[2] = dpp_addf<0x4E>(acc[2]); acc[3] = dpp_addf<0x4E>(acc[3]);
                if (kc == 0) {
                    float i_ = fast_sigmoid(acc[0] + bias0);
                    float f_ = fast_sigmoid(acc[1] + bias1);
                    float g_ = fast_tanh   (acc[2] + bias2);
                    float o_ = fast_sigmoid(acc[3] + bias3);
                    c_st = f_ * c_st + i_ * g_;
                    float h = o_ * fast_tanh(c_st);
                    myBuf[wb][(2 + (j >> 5)) * 36 + (j & 31)] = h;      // own h
                    if (role == 1)
                        bufL2[wb][(j >> 5) * 36 + (j & 31)] = h;        // L2's x
                    else
                        hout[((long)b * T_ + (s - 2)) * H_ + j] = h;
                }
            }
        }
        block_sync_lds();
    }
}

// ---------------------------------------------------------------------------
// K2': diagonal PAIR [L3+L4], both heavy roles. L3 t=s (x = h_L2 from global,
// prefetched), L4 t=s-1 (x = h_L3 via LDS). In-place on buf: L3 reads row s+1
// at step s, L4 overwrites row s-1 at step s -> 2-round gap.
// ---------------------------------------------------------------------------
__global__ __attribute__((amdgpu_flat_work_group_size(512, 512)))
void lstm_pair34(const float* __restrict__ xin,   // [B,T,64] h_L2 (aliases hout)
                 float* __restrict__ hout,        // [B,T,64] h_L4
                 const float* __restrict__ wih3, const float* __restrict__ whh3,
                 const float* __restrict__ bih3, const float* __restrict__ bhh3,
                 const float* __restrict__ wih4, const float* __restrict__ whh4,
                 const float* __restrict__ bih4, const float* __restrict__ bhh4)
{
    const int b    = blockIdx.x;
    const int tid  = threadIdx.x;
    const int role = tid >> 8;      // 0=L3, 1=L4 (wave-uniform)
    const int loc  = tid & 255;
    const int kc   = loc & 3;
    const int j    = loc >> 2;

    __shared__ __align__(16) float bufL3[2][144];
    __shared__ __align__(16) float bufL4[2][144];

    const float* wih = (role == 0) ? wih3 : wih4;
    const float* whh = (role == 0) ? whh3 : whh4;
    const float* bih = (role == 0) ? bih3 : bih4;
    const float* bhh = (role == 0) ? bhh3 : bhh4;
    float (*myBuf)[144] = (role == 0) ? bufL3 : bufL4;

    f32x4 wt[4][8];
    load_w_heavy(wih, whh, j, kc, wt);

    float bias0 = 0.f, bias1 = 0.f, bias2 = 0.f, bias3 = 0.f;
    if (kc == 0) {
        bias0 = bih[0*H_+j] + bhh[0*H_+j];
        bias1 = bih[1*H_+j] + bhh[1*H_+j];
        bias2 = bih[2*H_+j] + bhh[2*H_+j];
        bias3 = bih[3*H_+j] + bhh[3*H_+j];
    }
    float c_st = 0.f;

    // LDS init: L3 reads parity 0 at s=0 (x row 0 + h=0); L4 parity 1 at s=1.
    if (tid < H_) {
        const int u = tid;
        bufL3[0][(u >> 5) * 36 + (u & 31)] = xin[(long)b * T_ * H_ + u];
        bufL3[0][(2 + (u >> 5)) * 36 + (u & 31)] = 0.f;
    } else if (tid < 128) {
        const int u = tid - 64;
        bufL4[1][(2 + (u >> 5)) * 36 + (u & 31)] = 0.f;
    }
    block_sync_lds();

    for (int s = 0; s <= T_; ++s) {
        const int rb = s & 1, wb = rb ^ 1;
        const bool active = (role == 0) ? (s < T_) : (s >= 1);
        if (active) {
            // L3: prefetch next x row (kc==1 lanes, one float each)
            float xn = 0.f;
            if (role == 0 && kc == 1 && s + 1 < T_)
                xn = xin[((long)b * T_ + s + 1) * H_ + j];

            float acc[4];
            dot4x32(&myBuf[rb][kc * 36], wt, acc);
            acc[0] = dpp_addf<0xB1>(acc[0]); acc[1] = dpp_addf<0xB1>(acc[1]);
            acc[2] = dpp_addf<0xB1>(acc[2]); acc[3] = dpp_addf<0xB1>(acc[3]);
            acc[0] = dpp_addf<0x4E>(acc[0]); acc[1] = dpp_addf<0x4E>(acc[1]);
            acc[2] = dpp_addf<0x4E>(acc[2]); acc[3] = dpp_addf<0x4E>(acc[3]);

            if (kc == 0) {
                float i_ = fast_sigmoid(acc[0] + bias0);
                float f_ = fast_sigmoid(acc[1] + bias1);
                float g_ = fast_tanh   (acc[2] + bias2);
                float o_ = fast_sigmoid(acc[3] + bias3);
                c_st = f_ * c_st + i_ * g_;
                float h = o_ * fast_tanh(c_st);
                myBuf[wb][(2 + (j >> 5)) * 36 + (j & 31)] = h;          // own h
                if (role == 0)
                    bufL4[wb][(j >> 5) * 36 + (j & 31)] = h;            // L4's x
                else
                    hout[((long)b * T_ + (s - 1)) * H_ + j] = h;
            }
            if (role == 0 && kc == 1)
                bufL3[wb][(j >> 5) * 36 + (j & 31)] = xn;               // next x row
        }
        block_sync_lds();
    }
}

// MLP head (R3-R11-validated): wave-uniform W1 -> scalar loads. ~25 us.
__global__ __launch_bounds__(256)
void mlp_head_v2(const float* __restrict__ hbuf,
                 const float* __restrict__ W1,
                 const float* __restrict__ b1,
                 const float* __restrict__ W2,
                 const float* __restrict__ b2,
                 float* __restrict__ out)
{
    const long r = (long)blockIdx.x * 256 + threadIdx.x;

    float row[H_];
    const float4* src = (const float4*)(hbuf + r * H_);
    #pragma unroll
    for (int q = 0; q < 16; ++q) {
        float4 v = src[q];
        row[4*q+0] = fmaxf(v.x, 0.f); row[4*q+1] = fmaxf(v.y, 0.f);
        row[4*q+2] = fmaxf(v.z, 0.f); row[4*q+3] = fmaxf(v.w, 0.f);
    }
    #pragma unroll
    for (int q = 0; q < 16; ++q)
        asm volatile("" : "+v"(row[4*q]), "+v"(row[4*q+1]),
                         "+v"(row[4*q+2]), "+v"(row[4*q+3]));

    float acc = b2[0];
    for (int jj = 0; jj < H_; ++jj) {
        const float* wrow = W1 + jj * H_;
        float s0 = 0.f, s1 = 0.f, s2 = 0.f, s3 = 0.f;
        #pragma unroll
        for (int q = 0; q < 16; ++q) {
            s0 += row[4*q+0] * wrow[4*q+0];
            s1 += row[4*q+1] * wrow[4*q+1];
            s2 += row[4*q+2] * wrow[4*q+2];
            s3 += row[4*q+3] * wrow[4*q+3];
        }
        float y = fmaxf(b1[jj] + (s0 + s1) + (s2 + s3), 0.f);
        acc += y * W2[jj];
    }
    out[r] = acc;
}

extern "C" void kernel_launch(void* const* d_in, const int* in_sizes, int n_in,
                              void* d_out, int out_size, void* d_ws, size_t ws_size,
                              hipStream_t stream) {
    const float* x     = (const float*)d_in[0];   // [B,T,1]
    const float* w_ih0 = (const float*)d_in[1];   // [256]
    const float* w_ihr = (const float*)d_in[2];   // [4,256,64]
    const float* w_hh  = (const float*)d_in[3];   // [5,256,64]
    const float* b_ih  = (const float*)d_in[4];   // [5,256]
    const float* b_hh  = (const float*)d_in[5];   // [5,256]
    const float* W1    = (const float*)d_in[6];   // [64,64]
    const float* b1    = (const float*)d_in[7];   // [64]
    const float* W2    = (const float*)d_in[8];   // [64]
    const float* b2    = (const float*)d_in[9];   // [1]
    // d_in[10] = future (0)

    float* out = (float*)d_out;
    float* buf = (float*)d_ws;                    // [B,T,64] fp32 = 64 MB

    const long LW = 4L * H_ * H_;   // 16384 floats per layer weight block
    const long LB = 4L * H_;        // 256 floats per layer bias block

    // K1': [L0+L1+L2] diagonal triple -> buf = h_L2
    lstm_tri012<<<dim3(B_), dim3(768), 0, stream>>>(
        x, buf,
        w_ih0, w_hh + 0 * LW, b_ih + 0 * LB, b_hh + 0 * LB,
        w_ihr + 0 * LW, w_hh + 1 * LW, b_ih + 1 * LB, b_hh + 1 * LB,
        w_ihr + 1 * LW, w_hh + 2 * LW, b_ih + 2 * LB, b_hh + 2 * LB);

    // K2': [L3+L4] diagonal pair, in-place on buf -> buf = h_L4
    lstm_pair34<<<dim3(B_), dim3(512), 0, stream>>>(
        buf, buf,
        w_ihr + 2 * LW, w_hh + 3 * LW, b_ih + 3 * LB, b_hh + 3 * LB,
        w_ihr + 3 * LW, w_hh + 4 * LW, b_ih + 4 * LB, b_hh + 4 * LB);

    mlp_head_v2<<<dim3((B_ * T_) / 256), dim3(256), 0, stream>>>(
        buf, W1, b1, W2, b2, out);
}